// Round 6
// baseline (221.359 us; speedup 1.0000x reference)
//
#include <hip/hip_runtime.h>

typedef float v2f __attribute__((ext_vector_type(2)));

#define N_PTS  20000
#define NPAIR  (N_PTS / 2)                 // 10000
#define Q      8                           // queries per thread
#define QPB    (256 * Q)                   // 2048
#define NQB    ((N_PTS + QPB - 1) / QPB)   // 10
#define NSEG   64                          // ref segments
#define SEGP   ((NPAIR + NSEG - 1) / NSEG) // 157 pairs/segment
#define QB79   79                          // fallback

struct RefPair { v2f x, y, z, w; };        // {x0,x1}{y0,y1}{z0,z1}{sd0,sd1}, 32B

// ---- numpy-exact helpers ----
__device__ __forceinline__ float np_self_dot(float x, float y, float z) {
    return __fadd_rn(__fadd_rn(__fmul_rn(x, x), __fmul_rn(y, y)),
                     __fmul_rn(z, z));
}
__device__ __forceinline__ unsigned int ordmap(float f) {
    unsigned int b = __float_as_uint(f);
    return (b & 0x80000000u) ? ~b : (b | 0x80000000u);
}

// Pair-transposed packing of both clouds + atomic-key init.
__global__ __launch_bounds__(256) void chamfer_prep(
    const float* __restrict__ preds, const float* __restrict__ gts,
    RefPair* __restrict__ ppairs, RefPair* __restrict__ gpairs,
    unsigned long long* __restrict__ keys)
{
    int t = blockIdx.x * 256 + threadIdx.x;
    if (t < 2 * NPAIR) {
        const float* src = (t < NPAIR) ? preds : gts;
        RefPair*     dst = (t < NPAIR) ? ppairs : gpairs;
        int j  = (t < NPAIR) ? t : t - NPAIR;
        int i0 = 2 * j, i1 = 2 * j + 1;
        float x0 = src[i0*3+0], y0 = src[i0*3+1], z0 = src[i0*3+2];
        float x1 = src[i1*3+0], y1 = src[i1*3+1], z1 = src[i1*3+2];
        RefPair r;
        r.x.x = x0; r.x.y = x1;
        r.y.x = y0; r.y.y = y1;
        r.z.x = z0; r.z.y = z1;
        r.w.x = np_self_dot(x0, y0, z0);
        r.w.y = np_self_dot(x1, y1, z1);
        dst[j] = r;
    }
    if (t < 2 * N_PTS) keys[t] = ~0ULL;
}

// Main: 2 refs/iter via packed f32. Queries pre-doubled (exact x2):
//   d = fl( fl(sq+sr) - ( fl(2qx*rx) ⊕ fl(2qy*ry) ⊕ fl(2qz*rz) ) )
// equals numpy's fl(fl(xx+yy) - 2*fl(zz)) bit-exactly (x2 commutes with RN).
// contract(off) forbids FMA fusion so every op rounds like numpy.
__global__ __launch_bounds__(256, 4) void chamfer_main(
    const float* __restrict__ preds, const float* __restrict__ gts,
    const RefPair* __restrict__ ppairs, const RefPair* __restrict__ gpairs,
    unsigned long long* __restrict__ keys)
{
    #pragma clang fp contract(off)
    int bid = blockIdx.x;
    int dir = bid / (NQB * NSEG);
    int rem = bid - dir * (NQB * NSEG);
    int seg = rem / NQB;
    int qb  = rem - seg * NQB;

    // dir 0: queries = preds, refs = gts; dir 1: swapped
    const float*   qpts = (dir == 0) ? preds  : gts;
    const RefPair* rp   = (dir == 0) ? gpairs : ppairs;

    int qbase = qb * QPB + threadIdx.x;

#define LOADQ(n)                                                          \
    float qx##n, qy##n, qz##n, sq##n, best##n; int bidx##n;               \
    {   int q  = qbase + n * 256;                                         \
        int qc = (q < N_PTS) ? q : (N_PTS - 1);                           \
        float x = qpts[qc*3+0], y = qpts[qc*3+1], z = qpts[qc*3+2];       \
        qx##n = __fadd_rn(x, x); qy##n = __fadd_rn(y, y);                 \
        qz##n = __fadd_rn(z, z);                                          \
        sq##n = np_self_dot(x, y, z);                                     \
        best##n = 3.4e38f; bidx##n = 0; }
    LOADQ(0) LOADQ(1) LOADQ(2) LOADQ(3) LOADQ(4) LOADQ(5) LOADQ(6) LOADQ(7)
#undef LOADQ

    int j0 = seg * SEGP;
    int j1 = min(j0 + SEGP, NPAIR);

#define CHAIN(n)                                                          \
    {   v2f m0 = rx2 * qx##n;                                             \
        v2f m1 = ry2 * qy##n;                                             \
        v2f m2 = rz2 * qz##n;                                             \
        v2f zz = (m0 + m1) + m2;                                          \
        v2f dd = (rw2 + sq##n) - zz;                                      \
        float dlo = dd.x, dhi = dd.y;                                     \
        bool  hlt = dhi < dlo;                 /* tie -> lo (lower idx) */ \
        float dmin = hlt ? dhi : dlo;                                     \
        int   kmin = kk + (hlt ? 1 : 0);                                  \
        bool  blt = dmin < best##n;            /* tie -> earlier best */  \
        best##n = blt ? dmin : best##n;                                   \
        bidx##n = blt ? kmin : bidx##n; }

    #pragma unroll 2
    for (int j = j0; j < j1; ++j) {
        RefPair r = rp[j];                 // wave-uniform -> scalar loads
        v2f rx2 = r.x, ry2 = r.y, rz2 = r.z, rw2 = r.w;
        int kk  = 2 * j;
        CHAIN(0) CHAIN(1) CHAIN(2) CHAIN(3)
        CHAIN(4) CHAIN(5) CHAIN(6) CHAIN(7)
    }
#undef CHAIN

#define EMIT(n)                                                           \
    {   int q = qbase + n * 256;                                          \
        if (q < N_PTS) {                                                  \
            unsigned long long key =                                      \
                ((unsigned long long)ordmap(best##n) << 32) |             \
                (unsigned int)bidx##n;                                    \
            atomicMin(&keys[dir * N_PTS + q], key);                       \
        } }
    EMIT(0) EMIT(1) EMIT(2) EMIT(3) EMIT(4) EMIT(5) EMIT(6) EMIT(7)
#undef EMIT
}

__global__ __launch_bounds__(256) void chamfer_finalize(
    const unsigned long long* __restrict__ keys,
    float* __restrict__ out)
{
    int t = blockIdx.x * 256 + threadIdx.x;
    if (t >= 2 * N_PTS) return;
    int dir = t / N_PTS;
    int q   = t - dir * N_PTS;
    unsigned long long key = keys[dir * N_PTS + q];
    unsigned int hi = (unsigned int)(key >> 32);
    unsigned int lo = (unsigned int)(key & 0xFFFFFFFFu);
    unsigned int b  = (hi & 0x80000000u) ? (hi ^ 0x80000000u) : ~hi;
    out[dir * N_PTS + q]       = __uint_as_float(b);   // dist1 | dist2
    out[(2 + dir) * N_PTS + q] = (float)lo;            // idx1  | idx2
}

// ---- fallback (tiny workspace): direct kernel, correct but slow ----
__device__ __forceinline__ float np_pair(float sq, float sr,
                                         float qx, float qy, float qz,
                                         float rx, float ry, float rz) {
    float zz = __fadd_rn(__fadd_rn(__fmul_rn(qx, rx), __fmul_rn(qy, ry)),
                         __fmul_rn(qz, rz));
    return __fsub_rn(__fadd_rn(sq, sr), __fadd_rn(zz, zz));
}

__global__ __launch_bounds__(256) void chamfer_direct_kernel(
    const float* __restrict__ preds,
    const float* __restrict__ gts,
    float* __restrict__ out)
{
    __shared__ float4 spts[256];
    int bid = blockIdx.x;
    int dir = bid / QB79;
    int qb  = bid - dir * QB79;
    int q   = qb * 256 + threadIdx.x;

    const float* qpts = (dir == 0) ? preds : gts;
    const float* rpts = (dir == 0) ? gts   : preds;

    int qc = (q < N_PTS) ? q : (N_PTS - 1);
    float qx = qpts[qc*3+0], qy = qpts[qc*3+1], qz = qpts[qc*3+2];
    float sq = np_self_dot(qx, qy, qz);
    float best = 3.4e38f;
    int   bidx = 0;

    for (int t = 0; t < N_PTS; t += 256) {
        int cnt = min(256, N_PTS - t);
        __syncthreads();
        if ((int)threadIdx.x < cnt) {
            int j = t + threadIdx.x;
            float rx = rpts[j*3+0], ry = rpts[j*3+1], rz = rpts[j*3+2];
            spts[threadIdx.x] = make_float4(rx, ry, rz, np_self_dot(rx, ry, rz));
        }
        __syncthreads();
        for (int k = 0; k < cnt; ++k) {
            float4 r = spts[k];
            float d = np_pair(sq, r.w, qx, qy, qz, r.x, r.y, r.z);
            if (d < best) { best = d; bidx = t + k; }
        }
    }
    if (q < N_PTS) {
        out[dir * N_PTS + q]       = best;
        out[(2 + dir) * N_PTS + q] = (float)bidx;
    }
}

extern "C" void kernel_launch(void* const* d_in, const int* in_sizes, int n_in,
                              void* d_out, int out_size, void* d_ws, size_t ws_size,
                              hipStream_t stream) {
    const float* preds = (const float*)d_in[0];  // [20000, 3]
    const float* gts   = (const float*)d_in[1];  // [1, 20000, 3]
    float* out = (float*)d_out;

    size_t pair_bytes = (size_t)NPAIR * sizeof(RefPair);                   // 320 KB
    size_t keys_bytes = (size_t)2 * N_PTS * sizeof(unsigned long long);    // 320 KB
    size_t need = 2 * pair_bytes + keys_bytes;                             // 960 KB

    if (ws_size >= need) {
        RefPair* ppairs = (RefPair*)d_ws;
        RefPair* gpairs = (RefPair*)((char*)d_ws + pair_bytes);
        unsigned long long* keys =
            (unsigned long long*)((char*)d_ws + 2 * pair_bytes);

        chamfer_prep<<<(2 * N_PTS + 255) / 256, 256, 0, stream>>>(
            preds, gts, ppairs, gpairs, keys);
        chamfer_main<<<2 * NQB * NSEG, 256, 0, stream>>>(
            preds, gts, ppairs, gpairs, keys);            // 1280 blocks
        chamfer_finalize<<<(2 * N_PTS + 255) / 256, 256, 0, stream>>>(keys, out);
    } else {
        chamfer_direct_kernel<<<2 * QB79, 256, 0, stream>>>(preds, gts, out);
    }
}